// Round 5
// baseline (384.189 us; speedup 1.0000x reference)
//
#include <hip/hip_runtime.h>
#include <cstdint>

typedef float f32x4 __attribute__((ext_vector_type(4)));
typedef __bf16 bf16x8 __attribute__((ext_vector_type(8)));

__device__ inline unsigned short f2bf(float f) {
  union { float f; uint32_t u; } v; v.f = f;
  uint32_t u = v.u;
  return (unsigned short)((u + 0x7fffu + ((u >> 16) & 1u)) >> 16); // RNE
}

// ---------------------------------------------------------------------------
// Fragment-major ("flat") layout for a 128-row x 1024-K bf16 operand tile t:
// elem(row,k) -> t*131072 + (k>>5)*4096 + ((row>>6)&1)*2048 + ((row>>4)&3)*512
//                + (((k>>3)&3)*16 + (row&15))*8 + (k&7)
// so one wave's MFMA fragment load = 64 lanes x 16B fully coalesced (1KB).
// ---------------------------------------------------------------------------

// ---------------------------------------------------------------------------
// K1: transpose + bf16-cast + fragment-shuffle the 4 weight matrices.
// Wt[z] holds B^T(n,k)=W[k][n] in flat layout. Grid (8 nt, 16 k-slab, 4 z).
// ---------------------------------------------------------------------------
__global__ void prep_w(const float* __restrict__ wq, const float* __restrict__ wk,
                       const float* __restrict__ wv, const float* __restrict__ wo,
                       unsigned short* __restrict__ wt)
{
  __shared__ unsigned short Lt[128 * 72];   // [n_local 128][k_local 64] +8 pad
  const int z = blockIdx.z;
  const float* W = (z == 0) ? wq : (z == 1) ? wk : (z == 2) ? wv : wo;
  unsigned short* Wt = wt + (size_t)z * 1048576;
  const int nt = blockIdx.x;        // 0..7
  const int k0 = blockIdx.y * 64;   // 16 slabs of 64 k
  const int n0 = nt * 128;
  const int t = threadIdx.x;
#pragma unroll
  for (int p = 0; p < 8; p++) {
    int kr = p * 8 + (t >> 5);
    int nc = (t & 31) * 4;
    float4 f = *(const float4*)&W[(size_t)(k0 + kr) * 1024 + n0 + nc];
    Lt[(nc + 0) * 72 + kr] = f2bf(f.x);
    Lt[(nc + 1) * 72 + kr] = f2bf(f.y);
    Lt[(nc + 2) * 72 + kr] = f2bf(f.z);
    Lt[(nc + 3) * 72 + kr] = f2bf(f.w);
  }
  __syncthreads();
#pragma unroll
  for (int ktl = 0; ktl < 2; ktl++)
#pragma unroll
    for (int rep = 0; rep < 2; rep++) {
      int pos = rep * 256 + t;            // 0..511
      int half = pos >> 8, bn = (pos >> 6) & 3, lane = pos & 63;
      int row = half * 64 + bn * 16 + (lane & 15);
      int kc = ktl * 32 + (lane >> 4) * 8;
      uint4 v = *(const uint4*)&Lt[row * 72 + kc];
      *(uint4*)&Wt[(size_t)nt * 131072 + (blockIdx.y * 2 + ktl) * 4096 +
                   half * 2048 + bn * 512 + lane * 8] = v;
    }
}

// ---------------------------------------------------------------------------
// K1b: compose the two RoPE tables into one rotation table (128 pos x 32 pairs)
// ---------------------------------------------------------------------------
__global__ void comb_kernel(const float* __restrict__ ing, const float* __restrict__ seq,
                            float* __restrict__ cosc, float* __restrict__ sinc)
{
  int idx = blockIdx.x * 256 + threadIdx.x; // 0..4095
  int j = idx >> 5, i = idx & 31;
  float s1 = ing[j * 64 + i], c1 = ing[j * 64 + 32 + i];
  float s2 = seq[j * 64 + i], c2 = seq[j * 64 + 32 + i];
  cosc[idx] = c1 * c2 - s1 * s2;   // cos(t1+t2)
  sinc[idx] = s1 * c2 + c1 * s2;   // sin(t1+t2)
}

// ---------------------------------------------------------------------------
// K2: fp32 -> bf16 conversion + fragment-shuffle of queries/keys/values.
// Grid (64 mt, 8 col-slab, 3 z). LDS transpose keeps both sides coalesced.
// ---------------------------------------------------------------------------
__global__ void cvt_kernel(const float* __restrict__ q, const float* __restrict__ k,
                           const float* __restrict__ v, unsigned short* __restrict__ dst)
{
  __shared__ unsigned short Lt[128 * 136];  // [row 128][col 128] +8 pad
  const int z = blockIdx.z;
  const float* src = (z == 0) ? q : (z == 1) ? k : v;
  unsigned short* d = dst + (size_t)z * 8388608 + (size_t)blockIdx.x * 131072;
  const int kc = blockIdx.y;        // col slab [kc*128, +128)
  const int t = threadIdx.x;
#pragma unroll
  for (int p = 0; p < 16; p++) {
    int row = p * 8 + (t >> 5);
    int col = (t & 31) * 4;
    float4 f = *(const float4*)&src[((size_t)blockIdx.x * 128 + row) * 1024 + kc * 128 + col];
    ushort4 u;
    u.x = f2bf(f.x); u.y = f2bf(f.y); u.z = f2bf(f.z); u.w = f2bf(f.w);
    *(ushort4*)&Lt[row * 136 + col] = u;
  }
  __syncthreads();
#pragma unroll
  for (int ktl = 0; ktl < 4; ktl++)
#pragma unroll
    for (int rep = 0; rep < 2; rep++) {
      int pos = rep * 256 + t;           // 0..511
      int half = pos >> 8, a = (pos >> 6) & 3, lane = pos & 63;
      int row = half * 64 + a * 16 + (lane & 15);
      int c = ktl * 32 + (lane >> 4) * 8;
      uint4 vv = *(const uint4*)&Lt[row * 136 + c];
      *(uint4*)&d[(size_t)(kc * 4 + ktl) * 4096 + half * 2048 + a * 512 + lane * 8] = vv;
    }
}

// ---------------------------------------------------------------------------
// K3/K5: flatmm-style 128x128-tile bf16 GEMM. Both operands pre-shuffled to
// fragment-major layout -> each fragment is one coalesced global_load_dwordx4
// from L2. NO LDS, NO barriers, no vmcnt(0) drains: compiler pipelines loads
// with fine-grained per-register vmcnt (the thing the global_load_lds
// structure cannot express). Grid M-fastest for XCD-local A reuse.
//   final_mode=0: z in {0,1,2} -> Q(+RoPE), K(+RoPE), V(transposed) epilogues
//   final_mode=1: plain fp32 out + bias (nontemporal)
// ---------------------------------------------------------------------------
__global__ __launch_bounds__(256, 4)
void gemm_flat(const unsigned short* __restrict__ Abase,
               const unsigned short* __restrict__ Bbase,
               const float* __restrict__ b0, const float* __restrict__ b1,
               const float* __restrict__ b2,
               unsigned short* __restrict__ qb, unsigned short* __restrict__ kb,
               unsigned short* __restrict__ vtb,
               float* __restrict__ outf,
               const float* __restrict__ cosc, const float* __restrict__ sinc,
               int final_mode)
{
  const int tid = threadIdx.x;
  const int lane = tid & 63;
  const int wave = tid >> 6;
  const int quad = lane >> 4;
  const int l15 = lane & 15;

  const int z = blockIdx.z;
  const int mt = blockIdx.x;        // M fastest -> XCD-local A reuse
  const int nt = blockIdx.y;

  const unsigned short* A = Abase + (size_t)z * 8388608 + (size_t)mt * 131072 +
                            (wave >> 1) * 2048 + lane * 8;
  const unsigned short* B = Bbase + (size_t)z * 1048576 + (size_t)nt * 131072 +
                            (wave & 1) * 2048 + lane * 8;

  f32x4 acc[4][4];
#pragma unroll
  for (int a = 0; a < 4; a++)
#pragma unroll
    for (int n = 0; n < 4; n++)
      acc[a][n] = (f32x4){0.f, 0.f, 0.f, 0.f};

#pragma unroll 4
  for (int kt = 0; kt < 32; kt++) {
    bf16x8 af[4], bfr[4];
#pragma unroll
    for (int a = 0; a < 4; a++)
      af[a] = *(const bf16x8*)(A + kt * 4096 + a * 512);
#pragma unroll
    for (int n = 0; n < 4; n++)
      bfr[n] = *(const bf16x8*)(B + kt * 4096 + n * 512);
#pragma unroll
    for (int a = 0; a < 4; a++)
#pragma unroll
      for (int n = 0; n < 4; n++)
        acc[a][n] = __builtin_amdgcn_mfma_f32_16x16x32_bf16(af[a], bfr[n], acc[a][n], 0, 0, 0);
  }

  // ---------------- epilogue ----------------
  const int tileM = mt * 128, tileN = nt * 128;
  const int wm = (wave >> 1) * 64, wn = (wave & 1) * 64;
  if (final_mode) {
#pragma unroll
    for (int n = 0; n < 4; n++) {
      int cg = tileN + wn + n * 16 + l15;
      float bias = b0[cg];
#pragma unroll
      for (int a = 0; a < 4; a++)
#pragma unroll
        for (int reg = 0; reg < 4; reg++) {
          int r = tileM + wm + a * 16 + quad * 4 + reg;
          __builtin_nontemporal_store(acc[a][n][reg] + bias, &outf[(size_t)r * 1024 + cg]);
        }
    }
  } else {
    const float* bias = (z == 0) ? b0 : (z == 1) ? b1 : b2;
    unsigned short* outq = (z == 0) ? qb : kb;
#pragma unroll
    for (int n = 0; n < 4; n++) {
      int cg = tileN + wn + n * 16 + l15;
      float bv_ = bias[cg];
      int h = cg >> 6, e = cg & 63;
#pragma unroll
      for (int a = 0; a < 4; a++)
#pragma unroll
        for (int reg = 0; reg < 4; reg++) {
          int r = tileM + wm + a * 16 + quad * 4 + reg;
          int bb = r >> 7, l = r & 127;
          float v = acc[a][n][reg] + bv_;
          if (z == 2) {
            // V: store transposed [B,H,E,S] for contiguous PV B-fragments
            vtb[(((size_t)bb * 16 + h) * 64 + e) * 128 + l] = f2bf(v);
          } else {
            // fused RoPE: cols sit in lane pairs (lane^1 = col^1)
            float other = __shfl_xor(v, 1);
            float cs = cosc[l * 32 + (e >> 1)];
            float sn = sinc[l * 32 + (e >> 1)];
            float res = v * cs + ((e & 1) ? other : -other) * sn;
            outq[(((size_t)bb * 16 + h) * 128 + l) * 64 + e] = f2bf(res);
          }
        }
    }
  }
}

// ---------------------------------------------------------------------------
// K4: attention (R2 shape: one block per (b,h), 128 Q-rows). Scores in
// registers, 16-lane shuffle softmax, fp32 attn out, P via LDS into PV MFMA.
// O written directly in the flat fragment-major layout for the final GEMM.
// ---------------------------------------------------------------------------
__global__ __launch_bounds__(256, 2)
void attn_kernel(const unsigned short* __restrict__ qb,
                 const unsigned short* __restrict__ kb,
                 const unsigned short* __restrict__ vtb,
                 const unsigned char* __restrict__ mask,
                 float* __restrict__ attn_out,
                 unsigned short* __restrict__ ob)
{
  __shared__ __attribute__((aligned(16))) unsigned short Pb[128 * 136]; // +8 pad
  const int tid = threadIdx.x;
  const int lane = tid & 63;
  const int wave = tid >> 6;
  const int quad = lane >> 4;
  const int l15 = lane & 15;
  const int bh = blockIdx.x;       // b*16 + h
  const int b = bh >> 4;
  const int h = bh & 15;

  const unsigned short* q = qb + (size_t)bh * 128 * 64;
  const unsigned short* k = kb + (size_t)bh * 128 * 64;
  const unsigned short* vt = vtb + (size_t)bh * 64 * 128;

  // ---- scores = Q K^T : each wave owns 32 rows (2 m-tiles x 8 n-tiles) ----
  f32x4 sacc[2][8];
#pragma unroll
  for (int mt = 0; mt < 2; mt++)
#pragma unroll
    for (int nt = 0; nt < 8; nt++)
      sacc[mt][nt] = (f32x4){0.f, 0.f, 0.f, 0.f};

#pragma unroll
  for (int ks = 0; ks < 2; ks++) {
    bf16x8 aq[2], bk[8];
#pragma unroll
    for (int mt = 0; mt < 2; mt++)
      aq[mt] = *(const bf16x8*)&q[(size_t)(wave * 32 + mt * 16 + l15) * 64 + ks * 32 + quad * 8];
#pragma unroll
    for (int nt = 0; nt < 8; nt++)
      bk[nt] = *(const bf16x8*)&k[(size_t)(nt * 16 + l15) * 64 + ks * 32 + quad * 8];
#pragma unroll
    for (int mt = 0; mt < 2; mt++)
#pragma unroll
      for (int nt = 0; nt < 8; nt++)
        sacc[mt][nt] = __builtin_amdgcn_mfma_f32_16x16x32_bf16(aq[mt], bk[nt], sacc[mt][nt], 0, 0, 0);
  }

  // ---- softmax per row (row r lives in one 16-lane group, one reg) ----
  const float scale = 0.125f;
#pragma unroll
  for (int mt = 0; mt < 2; mt++) {
#pragma unroll
    for (int reg = 0; reg < 4; reg++) {
      int r = wave * 32 + mt * 16 + quad * 4 + reg;
      const unsigned char* mrow = mask + ((size_t)b * 128 + r) * 128;
      float sv[8];
#pragma unroll
      for (int nt = 0; nt < 8; nt++) {
        float x = sacc[mt][nt][reg] * scale;
        if (mrow[nt * 16 + l15]) x = -__builtin_inff();
        sv[nt] = x;
      }
      float m = sv[0];
#pragma unroll
      for (int nt = 1; nt < 8; nt++) m = fmaxf(m, sv[nt]);
#pragma unroll
      for (int off = 1; off < 16; off <<= 1) m = fmaxf(m, __shfl_xor(m, off));
      float s = 0.f;
#pragma unroll
      for (int nt = 0; nt < 8; nt++) { sv[nt] = __expf(sv[nt] - m); s += sv[nt]; }
#pragma unroll
      for (int off = 1; off < 16; off <<= 1) s += __shfl_xor(s, off);
      float inv = 1.0f / s;
      float* arow = attn_out + ((size_t)bh * 128 + r) * 128;
#pragma unroll
      for (int nt = 0; nt < 8; nt++) {
        float p = sv[nt] * inv;
        arow[nt * 16 + l15] = p;                    // required fp32 attn output
        Pb[r * 136 + nt * 16 + l15] = f2bf(p);      // bf16 P for PV MFMA
      }
    }
  }
  __syncthreads();

  // ---- O = P V ----
  f32x4 oacc[2][4];
#pragma unroll
  for (int mt = 0; mt < 2; mt++)
#pragma unroll
    for (int nt = 0; nt < 4; nt++)
      oacc[mt][nt] = (f32x4){0.f, 0.f, 0.f, 0.f};

#pragma unroll
  for (int ks = 0; ks < 4; ks++) {
    bf16x8 bv[4], ap[2];
#pragma unroll
    for (int nt = 0; nt < 4; nt++)
      bv[nt] = *(const bf16x8*)&vt[(size_t)(nt * 16 + l15) * 128 + ks * 32 + quad * 8];
#pragma unroll
    for (int mt = 0; mt < 2; mt++)
      ap[mt] = *(const bf16x8*)&Pb[(size_t)(wave * 32 + mt * 16 + l15) * 136 + ks * 32 + quad * 8];
#pragma unroll
    for (int mt = 0; mt < 2; mt++)
#pragma unroll
      for (int nt = 0; nt < 4; nt++)
        oacc[mt][nt] = __builtin_amdgcn_mfma_f32_16x16x32_bf16(ap[mt], bv[nt], oacc[mt][nt], 0, 0, 0);
  }

  // ---- write O in flat fragment-major layout (A operand of final GEMM) ----
  // m = b*128 + r, c = h*64 + e
#pragma unroll
  for (int mt = 0; mt < 2; mt++)
#pragma unroll
    for (int nt = 0; nt < 4; nt++)
#pragma unroll
      for (int reg = 0; reg < 4; reg++) {
        int r = wave * 32 + mt * 16 + quad * 4 + reg;
        int c = h * 64 + nt * 16 + l15;
        size_t addr = (size_t)b * 131072 + (c >> 5) * 4096 + ((r >> 6) & 1) * 2048 +
                      ((r >> 4) & 3) * 512 + ((((c >> 3) & 3) * 16) + (r & 15)) * 8 + (c & 7);
        ob[addr] = f2bf(oacc[mt][nt][reg]);
      }
}

// ---------------------------------------------------------------------------
extern "C" void kernel_launch(void* const* d_in, const int* in_sizes, int n_in,
                              void* d_out, int out_size, void* d_ws, size_t ws_size,
                              hipStream_t stream)
{
  const float* queries = (const float*)d_in[0];
  const float* keys    = (const float*)d_in[1];
  const float* values  = (const float*)d_in[2];
  const unsigned char* mask = (const unsigned char*)d_in[3];
  const float* Wq = (const float*)d_in[4];
  const float* bq = (const float*)d_in[5];
  const float* Wk = (const float*)d_in[6];
  const float* bk = (const float*)d_in[7];
  const float* Wv = (const float*)d_in[8];
  const float* bv = (const float*)d_in[9];
  const float* Wo = (const float*)d_in[10];
  const float* bo = (const float*)d_in[11];
  const float* ping = (const float*)d_in[12];
  const float* pseq = (const float*)d_in[13];

  float* out  = (float*)d_out;           // [8192,1024] fp32
  float* attn = out + 8388608;           // [64,16,128,128] fp32 (64 MB)
  // use the attn region as scratch for flat-shuffled bf16 inputs (48 MB)
  unsigned short* Xs = (unsigned short*)attn;

  char* ws = (char*)d_ws;
  unsigned short* Wt  = (unsigned short*)(ws);                          // 8 MB
  float* cosc = (float*)(ws + 8388608);                                 // 16 KB
  float* sinc = (float*)(ws + 8388608 + 16384);                         // 16 KB
  unsigned short* qbuf = (unsigned short*)(ws + 8421376);               // 16 MB
  unsigned short* kbuf = (unsigned short*)(ws + 8421376 + 16777216);    // 16 MB
  unsigned short* vtbuf= (unsigned short*)(ws + 8421376 + 2*16777216);  // 16 MB
  unsigned short* obuf = (unsigned short*)(ws + 8421376 + 3*16777216);  // 16 MB

  prep_w<<<dim3(8, 16, 4), 256, 0, stream>>>(Wq, Wk, Wv, Wo, Wt);
  comb_kernel<<<16, 256, 0, stream>>>(ping, pseq, cosc, sinc);
  cvt_kernel<<<dim3(64, 8, 3), 256, 0, stream>>>(queries, keys, values, Xs);
  gemm_flat<<<dim3(64, 8, 3), 256, 0, stream>>>(Xs, Wt, bq, bk, bv,
                                                qbuf, kbuf, vtbuf, nullptr,
                                                cosc, sinc, 0);
  attn_kernel<<<dim3(1024), 256, 0, stream>>>(qbuf, kbuf, vtbuf, mask, attn, obuf);
  gemm_flat<<<dim3(64, 8, 1), 256, 0, stream>>>(obuf, Wt + 3 * 1048576, bo, bo, bo,
                                                qbuf, kbuf, vtbuf, out,
                                                cosc, sinc, 1);
}